// Round 9
// baseline (111.046 us; speedup 1.0000x reference)
//
#include <hip/hip_runtime.h>
#include <hip/hip_bf16.h>
#include <cstddef>

// Problem constants
#define BB 8
#define CC 64
#define OO 64
#define HH 256
#define WW 256
#define MODES 16

// Workspace layout (float offsets)
#define WS_XBAR   0
#define WS_FTRE   262144
#define WS_FTIM   278528
#define WS_BOXRE  294912
#define WS_BOXIM  311296
#define WS_G      327680
#define WS_XBF    589824   // bf16 copy of x: [B*C][H*W] ushorts (67 MB), if ws fits

typedef __attribute__((ext_vector_type(8)))  short short8v;
typedef __attribute__((ext_vector_type(4)))  int   int4v;
typedef __attribute__((ext_vector_type(16))) float f32x16;

// f32 -> bf16 bits via HIP builtin (RNE). NO inline asm (round-7 lesson: the
// hand asm miscompiled under a pipelined schedule; builtin is safe and the
// compiler emits cvt_pk itself).
__device__ __forceinline__ unsigned short f2bf_u(float v) {
    return __builtin_bit_cast(unsigned short, __float2bfloat16(v));
}
__device__ __forceinline__ short f2bf_s(float v) {
    return (short)f2bf_u(v);
}

// ---------------------------------------------------------------------------
// K1: grid = B*C*4. Block j of slice bc handles rows [j*64, j*64+64):
//  - row means -> xbw[bc][h]
//  - column partial sums over its 64 rows -> partial[bc*4+j][w] (in d_out!)
//  - if WCOPY: bf16 copy of its stripe -> xbf (same [c][pixel] layout),
//    coalesced 8B/lane stores; cvt cost hides under the memory-bound pass.
template<bool WCOPY>
__global__ void k_means(const float* __restrict__ x,
                        float* __restrict__ xbw,        // [B*C][256]
                        float* __restrict__ partial,    // [B*C*4][256] (d_out)
                        unsigned short* __restrict__ xbf) {
    const int blk = blockIdx.x;                  // bc*4 + j
    const int bc  = blk >> 2;
    const int j   = blk & 3;
    const int t   = threadIdx.x;
    const int wave = t >> 6;
    const int lane = t & 63;
    const float* xs = x + (size_t)bc * (HH * WW);

    __shared__ float colsum[4][WW];

    float c0 = 0.f, c1 = 0.f, c2 = 0.f, c3 = 0.f;
    const int h0 = j * 64 + wave * 16;
    for (int r = 0; r < 16; ++r) {
        const int h = h0 + r;
        const float4 v = *reinterpret_cast<const float4*>(xs + (size_t)h * WW + lane * 4);
        c0 += v.x; c1 += v.y; c2 += v.z; c3 += v.w;
        if (WCOPY) {
            union { unsigned short u[4]; uint2 q; } pk;
            pk.u[0] = f2bf_u(v.x); pk.u[1] = f2bf_u(v.y);
            pk.u[2] = f2bf_u(v.z); pk.u[3] = f2bf_u(v.w);
            *reinterpret_cast<uint2*>(xbf + (size_t)bc * (HH * WW) +
                                      (size_t)h * WW + lane * 4) = pk.q;
        }
        float rs = (v.x + v.y) + (v.z + v.w);
        #pragma unroll
        for (int off = 32; off > 0; off >>= 1) rs += __shfl_xor(rs, off, 64);
        if (lane == 0) xbw[bc * HH + h] = rs * (1.0f / WW);
    }
    colsum[wave][lane * 4 + 0] = c0;
    colsum[wave][lane * 4 + 1] = c1;
    colsum[wave][lane * 4 + 2] = c2;
    colsum[wave][lane * 4 + 3] = c3;
    __syncthreads();
    partial[blk * WW + t] =
        (colsum[0][t] + colsum[1][t]) + (colsum[2][t] + colsum[3][t]);
}

// ---------------------------------------------------------------------------
// K2a: 16-mode ortho DFT. blk<512: row-mean vectors (xbw). blk>=512: column
// means assembled from the 4 partials (divide by H here).
__global__ void k_dft(const float* __restrict__ xbw,
                      const float* __restrict__ partial,
                      float* __restrict__ ftre,        // [1024][16]
                      float* __restrict__ ftim) {
    const int blk = blockIdx.x;
    const int t = threadIdx.x;
    __shared__ float vs[256];
    if (blk < 512) {
        vs[t] = xbw[(size_t)blk * 256 + t];
    } else {
        const int bc = blk - 512;
        vs[t] = ((partial[(bc * 4 + 0) * 256 + t] + partial[(bc * 4 + 1) * 256 + t]) +
                 (partial[(bc * 4 + 2) * 256 + t] + partial[(bc * 4 + 3) * 256 + t])) *
                (1.0f / HH);
    }
    __syncthreads();

    const int k = t >> 4;
    const int j = t & 15;
    float sre = 0.f, sim = 0.f;
    const float wk = 6.2831853071795864769f * (float)k / 256.0f;
    #pragma unroll
    for (int i = 0; i < 16; ++i) {
        const int h = j * 16 + i;
        float s, c;
        sincosf(wk * (float)h, &s, &c);
        sre += vs[h] * c;
        sim -= vs[h] * s;
    }
    #pragma unroll
    for (int m = 1; m < 16; m <<= 1) {
        sre += __shfl_xor(sre, m, 64);
        sim += __shfl_xor(sim, m, 64);
    }
    if (j == 0) {
        ftre[blk * MODES + k] = sre * (1.0f / 16.0f);
        ftim[blk * MODES + k] = sim * (1.0f / 16.0f);
    }
}

// ---------------------------------------------------------------------------
// K2b: channel mix in mode space.
__global__ void k_modemix(const float* __restrict__ ftre,
                          const float* __restrict__ ftim,
                          const float* __restrict__ wxr, const float* __restrict__ wxi,
                          const float* __restrict__ wyr, const float* __restrict__ wyi,
                          float* __restrict__ boxre, float* __restrict__ boxim) {
    const int blk = blockIdx.x;      // 0..15 : br = blk>>3, b = blk&7
    const int br  = blk >> 3;
    const int t   = threadIdx.x;

    const float* wr = br ? wyr : wxr;
    const float* wi = br ? wyi : wxi;

    __shared__ float fr[CC * MODES];
    __shared__ float fi[CC * MODES];
    #pragma unroll
    for (int i = 0; i < 4; ++i) {
        fr[t + i * 256] = ftre[blk * (CC * MODES) + t + i * 256];
        fi[t + i * 256] = ftim[blk * (CC * MODES) + t + i * 256];
    }
    __syncthreads();

    const int k  = t & 15;
    const int ob = t >> 4;
    #pragma unroll
    for (int p = 0; p < 4; ++p) {
        const int o = ob + p * 16;
        float are = 0.f, aim = 0.f;
        for (int c = 0; c < CC; ++c) {
            const float frv = fr[c * MODES + k];
            const float fiv = fi[c * MODES + k];
            const float wrv = wr[(c * OO + o) * MODES + k];
            const float wiv = wi[(c * OO + o) * MODES + k];
            are += frv * wrv - fiv * wiv;
            aim += frv * wiv + fiv * wrv;
        }
        boxre[blk * (OO * MODES) + o * MODES + k] = are;
        boxim[blk * (OO * MODES) + o * MODES + k] = aim;
    }
}

// ---------------------------------------------------------------------------
// K2c: inverse synthesis; mix_b folded into gx (br==0).
__global__ void k_synth(const float* __restrict__ boxre,
                        const float* __restrict__ boxim,
                        const float* __restrict__ mb,
                        float* __restrict__ g) {
    const int blk = blockIdx.x;      // (br*B+b)*64 + o
    const int t   = threadIdx.x;
    __shared__ float bre[MODES], bim[MODES];
    if (t < MODES)        bre[t] = boxre[(blk >> 6) * (OO * MODES) + (blk & 63) * MODES + t];
    else if (t < 2*MODES) bim[t - MODES] = boxim[(blk >> 6) * (OO * MODES) + (blk & 63) * MODES + (t - MODES)];
    __syncthreads();

    float acc = bre[0];
    const float wt = 6.2831853071795864769f * (float)t / 256.0f;
    #pragma unroll
    for (int k = 1; k < MODES; ++k) {
        float s, c;
        sincosf(wt * (float)k, &s, &c);
        acc += 2.0f * (bre[k] * c - bim[k] * s);
    }
    float v = acc * (1.0f / 16.0f);
    if (blk < BB * OO) v += mb[blk & 63];
    g[(size_t)blk * 256 + t] = v;
}

// ---------------------------------------------------------------------------
// K3 (bf16-input variant): MFMA epilogue GEMM reading the bf16 x-copy.
// out[b,o,h,w] = sum_c mw[o,c] xbf[b,c,h,w] + gx'[b,o,h] + gy[b,o,w]
// grid = B*256 (one h-row per block); 4 waves; wave wv covers pixels
// [wv*64, wv*64+64) as two 32-px tiles; ALL 64 o per tile from one gather.
// Gather = 32 ushort loads (2B/lane, L3-hot copy written by k_means).
// No cvt needed — just pack pairs into dwords. Flat gathers, single acc,
// no min-waves clamp (round-3 spill lesson).
__global__ void __launch_bounds__(256) k_final_mfma_bf16(
        const unsigned short* __restrict__ xbf,
        const float* __restrict__ mw,   // [O][C]
        const float* __restrict__ g,    // [2][B][O][256]
        float* __restrict__ out) {
    const int tid  = threadIdx.x;
    const int lane = tid & 63;
    const int wv   = tid >> 6;
    const int blk  = blockIdx.x;
    const int b    = blk >> 8;
    const int h    = blk & 255;
    const int nlo  = lane & 31;
    const int half = lane >> 5;

    const float* gx = g + (size_t)(b * OO) * 256;
    const float* gy = g + (size_t)BB * OO * 256 + (size_t)(b * OO) * 256;

    __shared__ float gxs[OO];
    if (tid < OO) gxs[tid] = gx[tid * 256 + h];

    // A fragments (weights) for both o-tiles, bf16, loaded once.
    short8v wf[2][4];
    #pragma unroll
    for (int ot = 0; ot < 2; ++ot) {
        const int o = ot * 32 + nlo;
        const float* wrow = mw + o * CC + 8 * half;
        #pragma unroll
        for (int kb = 0; kb < 4; ++kb) {
            short8v wi;
            #pragma unroll
            for (int i = 0; i < 8; ++i)
                wi[i] = f2bf_s(wrow[kb * 16 + i]);
            wf[ot][kb] = wi;
        }
    }
    __syncthreads();

    const unsigned short* xb = xbf + (size_t)b * CC * (HH * WW) + (size_t)h * WW;
    float*                ob = out + (size_t)b * OO * (HH * WW) + (size_t)h * WW;

    const int w0a = wv * 64;
    const int w0b = wv * 64 + 32;

    // ---- tile 0 gather: flat 32 ushort loads ----
    unsigned int xs[32];
    #pragma unroll
    for (int kb = 0; kb < 4; ++kb)
        #pragma unroll
        for (int i = 0; i < 8; ++i) {
            const int c = kb * 16 + 8 * half + i;
            xs[kb * 8 + i] = xb[(size_t)c * (HH * WW) + w0a + nlo];
        }

    // pack tile 0 (dword = lo | hi<<16; bf16 already)
    short8v xh[4];
    #pragma unroll
    for (int kb = 0; kb < 4; ++kb) {
        int4v xi;
        #pragma unroll
        for (int p = 0; p < 4; ++p)
            xi[p] = (int)(xs[kb * 8 + 2 * p] | (xs[kb * 8 + 2 * p + 1] << 16));
        xh[kb] = __builtin_bit_cast(short8v, xi);
    }

    // ---- tile 1 gather: issue now (WAR on xs), flies under tile-0 work ----
    #pragma unroll
    for (int kb = 0; kb < 4; ++kb)
        #pragma unroll
        for (int i = 0; i < 8; ++i) {
            const int c = kb * 16 + 8 * half + i;
            xs[kb * 8 + i] = xb[(size_t)c * (HH * WW) + w0b + nlo];
        }

    f32x16 acc;

    // ---- tile 0, o-tile 0 ----
    #pragma unroll
    for (int i = 0; i < 16; ++i) acc[i] = 0.f;
    #pragma unroll
    for (int kb = 0; kb < 4; ++kb)
        acc = __builtin_amdgcn_mfma_f32_32x32x16_bf16(wf[0][kb], xh[kb], acc, 0, 0, 0);
    #pragma unroll
    for (int r = 0; r < 16; ++r) {
        const int o = (r & 3) + 8 * (r >> 2) + 4 * half;
        const float v = acc[r] + gxs[o] + gy[o * 256 + w0a + nlo];
        __builtin_nontemporal_store(v, &ob[(size_t)o * (HH * WW) + w0a + nlo]);
    }

    // ---- tile 0, o-tile 1 ----
    #pragma unroll
    for (int i = 0; i < 16; ++i) acc[i] = 0.f;
    #pragma unroll
    for (int kb = 0; kb < 4; ++kb)
        acc = __builtin_amdgcn_mfma_f32_32x32x16_bf16(wf[1][kb], xh[kb], acc, 0, 0, 0);
    #pragma unroll
    for (int r = 0; r < 16; ++r) {
        const int o = 32 + (r & 3) + 8 * (r >> 2) + 4 * half;
        const float v = acc[r] + gxs[o] + gy[o * 256 + w0a + nlo];
        __builtin_nontemporal_store(v, &ob[(size_t)o * (HH * WW) + w0a + nlo]);
    }

    // ---- tile 1: pack (loads landed), both o-tiles ----
    #pragma unroll
    for (int kb = 0; kb < 4; ++kb) {
        int4v xi;
        #pragma unroll
        for (int p = 0; p < 4; ++p)
            xi[p] = (int)(xs[kb * 8 + 2 * p] | (xs[kb * 8 + 2 * p + 1] << 16));
        xh[kb] = __builtin_bit_cast(short8v, xi);
    }

    #pragma unroll
    for (int i = 0; i < 16; ++i) acc[i] = 0.f;
    #pragma unroll
    for (int kb = 0; kb < 4; ++kb)
        acc = __builtin_amdgcn_mfma_f32_32x32x16_bf16(wf[0][kb], xh[kb], acc, 0, 0, 0);
    #pragma unroll
    for (int r = 0; r < 16; ++r) {
        const int o = (r & 3) + 8 * (r >> 2) + 4 * half;
        const float v = acc[r] + gxs[o] + gy[o * 256 + w0b + nlo];
        __builtin_nontemporal_store(v, &ob[(size_t)o * (HH * WW) + w0b + nlo]);
    }

    #pragma unroll
    for (int i = 0; i < 16; ++i) acc[i] = 0.f;
    #pragma unroll
    for (int kb = 0; kb < 4; ++kb)
        acc = __builtin_amdgcn_mfma_f32_32x32x16_bf16(wf[1][kb], xh[kb], acc, 0, 0, 0);
    #pragma unroll
    for (int r = 0; r < 16; ++r) {
        const int o = 32 + (r & 3) + 8 * (r >> 2) + 4 * half;
        const float v = acc[r] + gxs[o] + gy[o * 256 + w0b + nlo];
        __builtin_nontemporal_store(v, &ob[(size_t)o * (HH * WW) + w0b + nlo]);
    }
}

// ---------------------------------------------------------------------------
// K3 (f32 fallback, byte-identical logic to round 8's passing kernel): used
// only if ws_size can't hold the bf16 copy.
__global__ void __launch_bounds__(256) k_final_mfma_f32(
        const float* __restrict__ x,
        const float* __restrict__ mw,
        const float* __restrict__ g,
        float* __restrict__ out) {
    const int tid  = threadIdx.x;
    const int lane = tid & 63;
    const int wv   = tid >> 6;
    const int blk  = blockIdx.x;
    const int b    = blk >> 8;
    const int h    = blk & 255;
    const int nlo  = lane & 31;
    const int half = lane >> 5;

    const float* gx = g + (size_t)(b * OO) * 256;
    const float* gy = g + (size_t)BB * OO * 256 + (size_t)(b * OO) * 256;

    __shared__ float gxs[OO];
    if (tid < OO) gxs[tid] = gx[tid * 256 + h];

    short8v wf[2][4];
    #pragma unroll
    for (int ot = 0; ot < 2; ++ot) {
        const int o = ot * 32 + nlo;
        const float* wrow = mw + o * CC + 8 * half;
        #pragma unroll
        for (int kb = 0; kb < 4; ++kb) {
            short8v wi;
            #pragma unroll
            for (int i = 0; i < 8; ++i)
                wi[i] = f2bf_s(wrow[kb * 16 + i]);
            wf[ot][kb] = wi;
        }
    }
    __syncthreads();

    const float* xb = x + (size_t)b * CC * (HH * WW) + (size_t)h * WW;
    float*       ob = out + (size_t)b * OO * (HH * WW) + (size_t)h * WW;

    const int w0a = wv * 64;
    const int w0b = wv * 64 + 32;

    float xv[32];
    #pragma unroll
    for (int kb = 0; kb < 4; ++kb)
        #pragma unroll
        for (int i = 0; i < 8; ++i) {
            const int c = kb * 16 + 8 * half + i;
            xv[kb * 8 + i] = xb[(size_t)c * (HH * WW) + w0a + nlo];
        }

    short8v xh[4];
    #pragma unroll
    for (int kb = 0; kb < 4; ++kb) {
        short8v xi;
        #pragma unroll
        for (int i = 0; i < 8; ++i) xi[i] = f2bf_s(xv[kb * 8 + i]);
        xh[kb] = xi;
    }

    #pragma unroll
    for (int kb = 0; kb < 4; ++kb)
        #pragma unroll
        for (int i = 0; i < 8; ++i) {
            const int c = kb * 16 + 8 * half + i;
            xv[kb * 8 + i] = xb[(size_t)c * (HH * WW) + w0b + nlo];
        }

    f32x16 acc;

    #pragma unroll
    for (int i = 0; i < 16; ++i) acc[i] = 0.f;
    #pragma unroll
    for (int kb = 0; kb < 4; ++kb)
        acc = __builtin_amdgcn_mfma_f32_32x32x16_bf16(wf[0][kb], xh[kb], acc, 0, 0, 0);
    #pragma unroll
    for (int r = 0; r < 16; ++r) {
        const int o = (r & 3) + 8 * (r >> 2) + 4 * half;
        const float v = acc[r] + gxs[o] + gy[o * 256 + w0a + nlo];
        __builtin_nontemporal_store(v, &ob[(size_t)o * (HH * WW) + w0a + nlo]);
    }

    #pragma unroll
    for (int i = 0; i < 16; ++i) acc[i] = 0.f;
    #pragma unroll
    for (int kb = 0; kb < 4; ++kb)
        acc = __builtin_amdgcn_mfma_f32_32x32x16_bf16(wf[1][kb], xh[kb], acc, 0, 0, 0);
    #pragma unroll
    for (int r = 0; r < 16; ++r) {
        const int o = 32 + (r & 3) + 8 * (r >> 2) + 4 * half;
        const float v = acc[r] + gxs[o] + gy[o * 256 + w0a + nlo];
        __builtin_nontemporal_store(v, &ob[(size_t)o * (HH * WW) + w0a + nlo]);
    }

    #pragma unroll
    for (int kb = 0; kb < 4; ++kb) {
        short8v xi;
        #pragma unroll
        for (int i = 0; i < 8; ++i) xi[i] = f2bf_s(xv[kb * 8 + i]);
        xh[kb] = xi;
    }

    #pragma unroll
    for (int i = 0; i < 16; ++i) acc[i] = 0.f;
    #pragma unroll
    for (int kb = 0; kb < 4; ++kb)
        acc = __builtin_amdgcn_mfma_f32_32x32x16_bf16(wf[0][kb], xh[kb], acc, 0, 0, 0);
    #pragma unroll
    for (int r = 0; r < 16; ++r) {
        const int o = (r & 3) + 8 * (r >> 2) + 4 * half;
        const float v = acc[r] + gxs[o] + gy[o * 256 + w0b + nlo];
        __builtin_nontemporal_store(v, &ob[(size_t)o * (HH * WW) + w0b + nlo]);
    }

    #pragma unroll
    for (int i = 0; i < 16; ++i) acc[i] = 0.f;
    #pragma unroll
    for (int kb = 0; kb < 4; ++kb)
        acc = __builtin_amdgcn_mfma_f32_32x32x16_bf16(wf[1][kb], xh[kb], acc, 0, 0, 0);
    #pragma unroll
    for (int r = 0; r < 16; ++r) {
        const int o = 32 + (r & 3) + 8 * (r >> 2) + 4 * half;
        const float v = acc[r] + gxs[o] + gy[o * 256 + w0b + nlo];
        __builtin_nontemporal_store(v, &ob[(size_t)o * (HH * WW) + w0b + nlo]);
    }
}

// ---------------------------------------------------------------------------
extern "C" void kernel_launch(void* const* d_in, const int* in_sizes, int n_in,
                              void* d_out, int out_size, void* d_ws, size_t ws_size,
                              hipStream_t stream) {
    const float* x    = (const float*)d_in[0];
    const float* wxr  = (const float*)d_in[1];
    const float* wxi  = (const float*)d_in[2];
    const float* wyr  = (const float*)d_in[3];
    const float* wyi  = (const float*)d_in[4];
    const float* mixw = (const float*)d_in[5];
    const float* mixb = (const float*)d_in[6];
    float* out = (float*)d_out;
    float* ws  = (float*)d_ws;

    float* xbw   = ws + WS_XBAR;
    float* ftre  = ws + WS_FTRE;
    float* ftim  = ws + WS_FTIM;
    float* boxre = ws + WS_BOXRE;
    float* boxim = ws + WS_BOXIM;
    float* g     = ws + WS_G;
    float* partial = out;    // d_out as scratch: dead until k_final overwrites

    unsigned short* xbf = (unsigned short*)(ws + WS_XBF);
    const size_t need = (size_t)WS_XBF * 4 + (size_t)BB * CC * HH * WW * 2;
    const bool big_ws = ws_size >= need;

    if (big_ws) {
        k_means<true><<<BB * CC * 4, 256, 0, stream>>>(x, xbw, partial, xbf);
    } else {
        k_means<false><<<BB * CC * 4, 256, 0, stream>>>(x, xbw, partial, nullptr);
    }
    k_dft<<<2 * BB * CC, 256, 0, stream>>>(xbw, partial, ftre, ftim);
    k_modemix<<<2 * BB, 256, 0, stream>>>(ftre, ftim, wxr, wxi, wyr, wyi, boxre, boxim);
    k_synth<<<2 * BB * OO, 256, 0, stream>>>(boxre, boxim, mixb, g);
    if (big_ws) {
        k_final_mfma_bf16<<<BB * 256, 256, 0, stream>>>(xbf, mixw, g, out);
    } else {
        k_final_mfma_f32<<<BB * 256, 256, 0, stream>>>(x, mixw, g, out);
    }
}

// Round 10
// 108.480 us; speedup vs baseline: 1.0237x; 1.0237x over previous
//
#include <hip/hip_runtime.h>
#include <hip/hip_bf16.h>
#include <cstddef>

// Problem constants
#define BB 8
#define CC 64
#define OO 64
#define HH 256
#define WW 256
#define MODES 16

// Workspace layout (float offsets)
#define WS_XBAR   0
#define WS_FTRE   262144
#define WS_FTIM   278528
#define WS_BOXRE  294912
#define WS_BOXIM  311296
#define WS_G      327680

typedef __attribute__((ext_vector_type(8)))  short short8v;
typedef __attribute__((ext_vector_type(16))) float f32x16;

// f32 -> bf16 bits via HIP builtin (RNE). NO inline asm (round-7 lesson: the
// hand asm miscompiled under a pipelined schedule; the compiler emits cvt_pk
// itself from scalar casts).
__device__ __forceinline__ short f2bf_s(float v) {
    return (short)__builtin_bit_cast(unsigned short, __float2bfloat16(v));
}

// ---------------------------------------------------------------------------
// K1: grid = B*C*4. Block j of slice bc handles rows [j*64, j*64+64):
//  - row means -> xbw[bc][h]
//  - column partial sums over its 64 rows -> partial[bc*4+j][w] (in d_out!)
// (round-9's bf16 x-copy removed: it cost k_means +67MB writes for a smaller
//  k_final gain — net regression.)
__global__ void k_means(const float* __restrict__ x,
                        float* __restrict__ xbw,       // [B*C][256]
                        float* __restrict__ partial) { // [B*C*4][256] (d_out scratch)
    const int blk = blockIdx.x;                  // bc*4 + j
    const int bc  = blk >> 2;
    const int j   = blk & 3;
    const int t   = threadIdx.x;
    const int wave = t >> 6;
    const int lane = t & 63;
    const float* xs = x + (size_t)bc * (HH * WW);

    __shared__ float colsum[4][WW];

    float c0 = 0.f, c1 = 0.f, c2 = 0.f, c3 = 0.f;
    const int h0 = j * 64 + wave * 16;
    for (int r = 0; r < 16; ++r) {
        const int h = h0 + r;
        const float4 v = *reinterpret_cast<const float4*>(xs + (size_t)h * WW + lane * 4);
        c0 += v.x; c1 += v.y; c2 += v.z; c3 += v.w;
        float rs = (v.x + v.y) + (v.z + v.w);
        #pragma unroll
        for (int off = 32; off > 0; off >>= 1) rs += __shfl_xor(rs, off, 64);
        if (lane == 0) xbw[bc * HH + h] = rs * (1.0f / WW);
    }
    colsum[wave][lane * 4 + 0] = c0;
    colsum[wave][lane * 4 + 1] = c1;
    colsum[wave][lane * 4 + 2] = c2;
    colsum[wave][lane * 4 + 3] = c3;
    __syncthreads();
    partial[blk * WW + t] =
        (colsum[0][t] + colsum[1][t]) + (colsum[2][t] + colsum[3][t]);
}

// ---------------------------------------------------------------------------
// K2a: 16-mode ortho DFT. blk<512: row-mean vectors (xbw). blk>=512: column
// means assembled from the 4 partials (divide by H here).
__global__ void k_dft(const float* __restrict__ xbw,
                      const float* __restrict__ partial,
                      float* __restrict__ ftre,        // [1024][16]
                      float* __restrict__ ftim) {
    const int blk = blockIdx.x;
    const int t = threadIdx.x;
    __shared__ float vs[256];
    if (blk < 512) {
        vs[t] = xbw[(size_t)blk * 256 + t];
    } else {
        const int bc = blk - 512;
        vs[t] = ((partial[(bc * 4 + 0) * 256 + t] + partial[(bc * 4 + 1) * 256 + t]) +
                 (partial[(bc * 4 + 2) * 256 + t] + partial[(bc * 4 + 3) * 256 + t])) *
                (1.0f / HH);
    }
    __syncthreads();

    const int k = t >> 4;
    const int j = t & 15;
    float sre = 0.f, sim = 0.f;
    const float wk = 6.2831853071795864769f * (float)k / 256.0f;
    #pragma unroll
    for (int i = 0; i < 16; ++i) {
        const int h = j * 16 + i;
        float s, c;
        sincosf(wk * (float)h, &s, &c);
        sre += vs[h] * c;
        sim -= vs[h] * s;
    }
    #pragma unroll
    for (int m = 1; m < 16; m <<= 1) {
        sre += __shfl_xor(sre, m, 64);
        sim += __shfl_xor(sim, m, 64);
    }
    if (j == 0) {
        ftre[blk * MODES + k] = sre * (1.0f / 16.0f);
        ftim[blk * MODES + k] = sim * (1.0f / 16.0f);
    }
}

// ---------------------------------------------------------------------------
// K2b: channel mix in mode space.
__global__ void k_modemix(const float* __restrict__ ftre,
                          const float* __restrict__ ftim,
                          const float* __restrict__ wxr, const float* __restrict__ wxi,
                          const float* __restrict__ wyr, const float* __restrict__ wyi,
                          float* __restrict__ boxre, float* __restrict__ boxim) {
    const int blk = blockIdx.x;      // 0..15 : br = blk>>3, b = blk&7
    const int br  = blk >> 3;
    const int t   = threadIdx.x;

    const float* wr = br ? wyr : wxr;
    const float* wi = br ? wyi : wxi;

    __shared__ float fr[CC * MODES];
    __shared__ float fi[CC * MODES];
    #pragma unroll
    for (int i = 0; i < 4; ++i) {
        fr[t + i * 256] = ftre[blk * (CC * MODES) + t + i * 256];
        fi[t + i * 256] = ftim[blk * (CC * MODES) + t + i * 256];
    }
    __syncthreads();

    const int k  = t & 15;
    const int ob = t >> 4;
    #pragma unroll
    for (int p = 0; p < 4; ++p) {
        const int o = ob + p * 16;
        float are = 0.f, aim = 0.f;
        for (int c = 0; c < CC; ++c) {
            const float frv = fr[c * MODES + k];
            const float fiv = fi[c * MODES + k];
            const float wrv = wr[(c * OO + o) * MODES + k];
            const float wiv = wi[(c * OO + o) * MODES + k];
            are += frv * wrv - fiv * wiv;
            aim += frv * wiv + fiv * wrv;
        }
        boxre[blk * (OO * MODES) + o * MODES + k] = are;
        boxim[blk * (OO * MODES) + o * MODES + k] = aim;
    }
}

// ---------------------------------------------------------------------------
// K2c: inverse synthesis; mix_b folded into gx (br==0).
__global__ void k_synth(const float* __restrict__ boxre,
                        const float* __restrict__ boxim,
                        const float* __restrict__ mb,
                        float* __restrict__ g) {
    const int blk = blockIdx.x;      // (br*B+b)*64 + o
    const int t   = threadIdx.x;
    __shared__ float bre[MODES], bim[MODES];
    if (t < MODES)        bre[t] = boxre[(blk >> 6) * (OO * MODES) + (blk & 63) * MODES + t];
    else if (t < 2*MODES) bim[t - MODES] = boxim[(blk >> 6) * (OO * MODES) + (blk & 63) * MODES + (t - MODES)];
    __syncthreads();

    float acc = bre[0];
    const float wt = 6.2831853071795864769f * (float)t / 256.0f;
    #pragma unroll
    for (int k = 1; k < MODES; ++k) {
        float s, c;
        sincosf(wt * (float)k, &s, &c);
        acc += 2.0f * (bre[k] * c - bim[k] * s);
    }
    float v = acc * (1.0f / 16.0f);
    if (blk < BB * OO) v += mb[blk & 63];
    g[(size_t)blk * 256 + t] = v;
}

// ---------------------------------------------------------------------------
// K3: MFMA epilogue GEMM with LDS-staged x (canonical §5 pattern).
// out[b,o,h,w] = sum_c mw[o,c] x[b,c,h,w] + gx'[b,o,h] + gy[b,o,w]
// grid = B*256 (one h-row per block); 4 waves.
// Stage: the block's x slab [64 c][256 w] f32 (64KB) via
// global_load_lds width-16: one 1KB channel-row per instruction (lane l
// supplies global addr row+16B*l; LDS dest = uniform base + l*16 — linear,
// per the wave-uniform-base rule). 16 DMA per wave, no VGPR round trip.
// Fragment gather then = ds_read_b32 from LDS: bank (w0+nlo)%32 ->
// lanes 0-31 all distinct banks, lanes 32-63 alias 2-way (free per m136).
// LDS 64.25KB -> 2 blocks/CU; block A's MFMA/stores overlap block B's DMA.
__global__ void __launch_bounds__(256) k_final_mfma(
        const float* __restrict__ x,
        const float* __restrict__ mw,   // [O][C]
        const float* __restrict__ g,    // [2][B][O][256]
        float* __restrict__ out) {
    const int tid  = threadIdx.x;
    const int lane = tid & 63;
    const int wv   = tid >> 6;
    const int blk  = blockIdx.x;
    const int b    = blk >> 8;
    const int h    = blk & 255;
    const int nlo  = lane & 31;
    const int half = lane >> 5;

    __shared__ float sx[CC * WW];    // 64KB staged x slab: [c][w]
    __shared__ float gxs[OO];

    const float* gx = g + (size_t)(b * OO) * 256;
    const float* gy = g + (size_t)BB * OO * 256 + (size_t)(b * OO) * 256;

    // gx[o,h] block-uniform hoist (issued before DMA so its wait is cheap)
    if (tid < OO) gxs[tid] = gx[tid * 256 + h];

    // async DMA stage: channel c row (1KB) per instruction
    const float* xrow = x + (size_t)b * CC * (HH * WW) + (size_t)h * WW;
    #pragma unroll
    for (int it = 0; it < 16; ++it) {
        const int c = wv * 16 + it;
        const float* gsrc = xrow + (size_t)c * (HH * WW) + lane * 4;
        __builtin_amdgcn_global_load_lds(
            (const __attribute__((address_space(1))) unsigned int*)gsrc,
            (__attribute__((address_space(3))) unsigned int*)&sx[c * WW],
            16, 0, 0);
    }

    // A fragments (weights) for both o-tiles, bf16 (converted while DMA flies)
    short8v wf[2][4];
    #pragma unroll
    for (int ot = 0; ot < 2; ++ot) {
        const int o = ot * 32 + nlo;
        const float* wrow = mw + o * CC + 8 * half;
        #pragma unroll
        for (int kb = 0; kb < 4; ++kb) {
            short8v wi;
            #pragma unroll
            for (int i = 0; i < 8; ++i)
                wi[i] = f2bf_s(wrow[kb * 16 + i]);
            wf[ot][kb] = wi;
        }
    }

    __syncthreads();   // compiler emits vmcnt(0) drain before s_barrier

    float* ob = out + (size_t)b * OO * (HH * WW) + (size_t)h * WW;
    const int w0a = wv * 64;
    const int w0b = wv * 64 + 32;

    // Fragment reads from LDS + cvt, both tiles upfront (LDS is cheap/flat).
    short8v xh0[4], xh1[4];
    #pragma unroll
    for (int kb = 0; kb < 4; ++kb) {
        short8v xa, xb_;
        #pragma unroll
        for (int i = 0; i < 8; ++i) {
            const int c = kb * 16 + 8 * half + i;
            xa[i]  = f2bf_s(sx[c * WW + w0a + nlo]);
            xb_[i] = f2bf_s(sx[c * WW + w0b + nlo]);
        }
        xh0[kb] = xa;
        xh1[kb] = xb_;
    }

    f32x16 acc;

    // ---- tile 0, o-tile 0 ----
    #pragma unroll
    for (int i = 0; i < 16; ++i) acc[i] = 0.f;
    #pragma unroll
    for (int kb = 0; kb < 4; ++kb)
        acc = __builtin_amdgcn_mfma_f32_32x32x16_bf16(wf[0][kb], xh0[kb], acc, 0, 0, 0);
    #pragma unroll
    for (int r = 0; r < 16; ++r) {
        const int o = (r & 3) + 8 * (r >> 2) + 4 * half;
        const float v = acc[r] + gxs[o] + gy[o * 256 + w0a + nlo];
        __builtin_nontemporal_store(v, &ob[(size_t)o * (HH * WW) + w0a + nlo]);
    }

    // ---- tile 0, o-tile 1 ----
    #pragma unroll
    for (int i = 0; i < 16; ++i) acc[i] = 0.f;
    #pragma unroll
    for (int kb = 0; kb < 4; ++kb)
        acc = __builtin_amdgcn_mfma_f32_32x32x16_bf16(wf[1][kb], xh0[kb], acc, 0, 0, 0);
    #pragma unroll
    for (int r = 0; r < 16; ++r) {
        const int o = 32 + (r & 3) + 8 * (r >> 2) + 4 * half;
        const float v = acc[r] + gxs[o] + gy[o * 256 + w0a + nlo];
        __builtin_nontemporal_store(v, &ob[(size_t)o * (HH * WW) + w0a + nlo]);
    }

    // ---- tile 1, o-tile 0 ----
    #pragma unroll
    for (int i = 0; i < 16; ++i) acc[i] = 0.f;
    #pragma unroll
    for (int kb = 0; kb < 4; ++kb)
        acc = __builtin_amdgcn_mfma_f32_32x32x16_bf16(wf[0][kb], xh1[kb], acc, 0, 0, 0);
    #pragma unroll
    for (int r = 0; r < 16; ++r) {
        const int o = (r & 3) + 8 * (r >> 2) + 4 * half;
        const float v = acc[r] + gxs[o] + gy[o * 256 + w0b + nlo];
        __builtin_nontemporal_store(v, &ob[(size_t)o * (HH * WW) + w0b + nlo]);
    }

    // ---- tile 1, o-tile 1 ----
    #pragma unroll
    for (int i = 0; i < 16; ++i) acc[i] = 0.f;
    #pragma unroll
    for (int kb = 0; kb < 4; ++kb)
        acc = __builtin_amdgcn_mfma_f32_32x32x16_bf16(wf[1][kb], xh1[kb], acc, 0, 0, 0);
    #pragma unroll
    for (int r = 0; r < 16; ++r) {
        const int o = 32 + (r & 3) + 8 * (r >> 2) + 4 * half;
        const float v = acc[r] + gxs[o] + gy[o * 256 + w0b + nlo];
        __builtin_nontemporal_store(v, &ob[(size_t)o * (HH * WW) + w0b + nlo]);
    }
}

// ---------------------------------------------------------------------------
extern "C" void kernel_launch(void* const* d_in, const int* in_sizes, int n_in,
                              void* d_out, int out_size, void* d_ws, size_t ws_size,
                              hipStream_t stream) {
    const float* x    = (const float*)d_in[0];
    const float* wxr  = (const float*)d_in[1];
    const float* wxi  = (const float*)d_in[2];
    const float* wyr  = (const float*)d_in[3];
    const float* wyi  = (const float*)d_in[4];
    const float* mixw = (const float*)d_in[5];
    const float* mixb = (const float*)d_in[6];
    float* out = (float*)d_out;
    float* ws  = (float*)d_ws;

    float* xbw   = ws + WS_XBAR;
    float* ftre  = ws + WS_FTRE;
    float* ftim  = ws + WS_FTIM;
    float* boxre = ws + WS_BOXRE;
    float* boxim = ws + WS_BOXIM;
    float* g     = ws + WS_G;
    float* partial = out;    // d_out as scratch: dead until k_final overwrites

    k_means<<<BB * CC * 4, 256, 0, stream>>>(x, xbw, partial);
    k_dft<<<2 * BB * CC, 256, 0, stream>>>(xbw, partial, ftre, ftim);
    k_modemix<<<2 * BB, 256, 0, stream>>>(ftre, ftim, wxr, wxi, wyr, wyi, boxre, boxim);
    k_synth<<<2 * BB * OO, 256, 0, stream>>>(boxre, boxim, mixb, g);
    k_final_mfma<<<BB * 256, 256, 0, stream>>>(x, mixw, g, out);
}

// Round 11
// 87.310 us; speedup vs baseline: 1.2719x; 1.2425x over previous
//
#include <hip/hip_runtime.h>
#include <hip/hip_bf16.h>
#include <cstddef>

// Problem constants
#define BB 8
#define CC 64
#define OO 64
#define HH 256
#define WW 256
#define MODES 16

// Workspace layout (float offsets)
//  [0)       pft [B*C][4][2][16][2]  131072   (per-stripe partial spectra)
//  [131072)  g   [2][B][O][256]      262144
#define WS_PFT 0
#define WS_G   131072

#define TWO_PI 6.2831853071795864769f

typedef __attribute__((ext_vector_type(8)))  short short8v;
typedef __attribute__((ext_vector_type(16))) float f32x16;

// f32 -> bf16 bits via HIP builtin (RNE). NO inline asm (round-7 lesson).
__device__ __forceinline__ short f2bf_s(float v) {
    return (short)__builtin_bit_cast(unsigned short, __float2bfloat16(v));
}

// ---------------------------------------------------------------------------
// K1: grid = B*C*4. Block j of slice bc handles rows [j*64, j*64+64).
// One pass over its stripe produces BOTH 16-mode partial spectra directly
// (DFT is linear; per-stripe partials sum to the full transform):
//   prow[k] = sum_{r<64} rowmean(h0+r) * e^{-i*2pi*k*(h0+r)/256}   (br=0)
//   pcol[k] = sum_{w}    colpartial(w) * e^{-i*2pi*k*w/256}        (br=1)
// Validated in round 6 (absmax 0.03125); round 6's regression was the
// 16-block k_spectral, not this kernel.
__global__ void k_means_dft(const float* __restrict__ x,
                            float* __restrict__ pft) { // [512][4][2][16][2]
    const int blk = blockIdx.x;                  // bc*4 + j
    const int bc  = blk >> 2;
    const int j   = blk & 3;
    const int t   = threadIdx.x;
    const int wave = t >> 6;
    const int lane = t & 63;
    const float* xs = x + (size_t)bc * (HH * WW);

    __shared__ float colsum[4][WW];
    __shared__ float cs[WW];
    __shared__ float rm[64];

    float c0 = 0.f, c1 = 0.f, c2 = 0.f, c3 = 0.f;
    const int h0 = j * 64 + wave * 16;
    for (int r = 0; r < 16; ++r) {
        const int h = h0 + r;
        const float4 v = *reinterpret_cast<const float4*>(xs + (size_t)h * WW + lane * 4);
        c0 += v.x; c1 += v.y; c2 += v.z; c3 += v.w;
        float rs = (v.x + v.y) + (v.z + v.w);
        #pragma unroll
        for (int off = 32; off > 0; off >>= 1) rs += __shfl_xor(rs, off, 64);
        if (lane == 0) rm[wave * 16 + r] = rs * (1.0f / WW);   // row mean
    }
    colsum[wave][lane * 4 + 0] = c0;
    colsum[wave][lane * 4 + 1] = c1;
    colsum[wave][lane * 4 + 2] = c2;
    colsum[wave][lane * 4 + 3] = c3;
    __syncthreads();
    cs[t] = (colsum[0][t] + colsum[1][t]) + (colsum[2][t] + colsum[3][t]);
    __syncthreads();

    // 16-mode partial DFTs. thread t: mode k = t>>4, sub-chunk = t&15.
    const int k   = t >> 4;
    const int sub = t & 15;
    const float wk = TWO_PI * (float)k / 256.0f;

    // column-branch: 256-point DFT of this stripe's column partial sums
    float cre = 0.f, cim = 0.f;
    #pragma unroll
    for (int i = 0; i < 16; ++i) {
        const int w = sub * 16 + i;
        float s, c;
        sincosf(wk * (float)w, &s, &c);
        cre += cs[w] * c;
        cim -= cs[w] * s;
    }
    // row-branch: 64-point partial DFT of this stripe's row means (global h!)
    float rre = 0.f, rim = 0.f;
    #pragma unroll
    for (int i = 0; i < 4; ++i) {
        const int r = sub * 4 + i;
        float s, c;
        sincosf(wk * (float)(j * 64 + r), &s, &c);
        rre += rm[r] * c;
        rim -= rm[r] * s;
    }
    #pragma unroll
    for (int m = 1; m < 16; m <<= 1) {
        cre += __shfl_xor(cre, m, 64);
        cim += __shfl_xor(cim, m, 64);
        rre += __shfl_xor(rre, m, 64);
        rim += __shfl_xor(rim, m, 64);
    }
    if (sub == 0) {
        float* p = pft + (((size_t)blk * 2 + 0) * 16 + k) * 2;
        p[0] = rre; p[1] = rim;
        p += 32;                         // br=1 slot
        p[0] = cre; p[1] = cim;
    }
}

// ---------------------------------------------------------------------------
// K2: fused modemix+synth, grid = 2*B*O = 1024 blocks (one per (br,b,o)).
// Each block: reduce the 4 stripe partials over its (br,b) -> ft[c][k],
// channel-mix into box[o][k], synthesize g[br,b,o,0..255]. mix_b folded in
// for br==0. Redundant pft re-reads across the 64 o-blocks of one (br,b)
// are L2-hot (~64MB total, ~2us).
__global__ void k_mixsynth(const float* __restrict__ pft,
                           const float* __restrict__ wxr, const float* __restrict__ wxi,
                           const float* __restrict__ wyr, const float* __restrict__ wyi,
                           const float* __restrict__ mb,
                           float* __restrict__ g) {
    const int blk = blockIdx.x;          // (br*8 + b)*64 + o
    const int bb  = blk >> 6;
    const int br  = bb >> 3;
    const int b   = bb & 7;
    const int o   = blk & 63;
    const int t   = threadIdx.x;
    const int k   = t & 15;
    const int cg  = t >> 4;              // 0..15, 4 channels each
    const int wave = t >> 6;
    const int lane = t & 63;

    const float* wr = br ? wyr : wxr;
    const float* wi = br ? wyi : wxi;
    // row branch: rm already /W, ortho 1/sqrt(256) -> 1/16
    // col branch: raw sums over h -> 1/256, ortho -> 1/16
    const float norm = br ? (1.0f / (16.0f * 256.0f)) : (1.0f / 16.0f);

    // partial box over this thread's 4 channels
    float are = 0.f, aim = 0.f;
    #pragma unroll
    for (int cc = 0; cc < 4; ++cc) {
        const int c = cg * 4 + cc;
        float re = 0.f, im = 0.f;
        #pragma unroll
        for (int j = 0; j < 4; ++j) {
            const float* p = pft +
                ((((size_t)(b * 64 + c) * 4 + j) * 2 + br) * 16 + k) * 2;
            re += p[0]; im += p[1];
        }
        re *= norm; im *= norm;
        const float wrv = wr[(c * OO + o) * MODES + k];
        const float wiv = wi[(c * OO + o) * MODES + k];
        are += re * wrv - im * wiv;
        aim += re * wiv + im * wrv;
    }
    // reduce over cg: wave holds cg {0..3}(+16 steps); then across 4 waves
    are += __shfl_xor(are, 16, 64); aim += __shfl_xor(aim, 16, 64);
    are += __shfl_xor(are, 32, 64); aim += __shfl_xor(aim, 32, 64);

    __shared__ float wre[4][16], wim[4][16];
    __shared__ float bre[16], bim[16];
    if (lane < 16) { wre[wave][lane] = are; wim[wave][lane] = aim; }
    __syncthreads();
    if (t < 16) {
        bre[t] = (wre[0][t] + wre[1][t]) + (wre[2][t] + wre[3][t]);
        bim[t] = (wim[0][t] + wim[1][t]) + (wim[2][t] + wim[3][t]);
    }
    __syncthreads();

    // synth: thread t = position
    float acc = bre[0];
    const float wt = TWO_PI * (float)t / 256.0f;
    #pragma unroll
    for (int kk = 1; kk < MODES; ++kk) {
        float s, c;
        sincosf(wt * (float)kk, &s, &c);
        acc += 2.0f * (bre[kk] * c - bim[kk] * s);
    }
    float v = acc * (1.0f / 16.0f);
    if (br == 0) v += mb[o];
    g[(size_t)blk * 256 + t] = v;
}

// ---------------------------------------------------------------------------
// K3: MFMA epilogue GEMM — round 8's register version, UNCHANGED (best
// measured of 5 variants; gather structure is not its limiter).
// out[b,o,h,w] = sum_c mw[o,c] x[b,c,h,w] + gx'[b,o,h] + gy[b,o,w]
__global__ void __launch_bounds__(256) k_final_mfma(
        const float* __restrict__ x,
        const float* __restrict__ mw,   // [O][C]
        const float* __restrict__ g,    // [2][B][O][256]
        float* __restrict__ out) {
    const int tid  = threadIdx.x;
    const int lane = tid & 63;
    const int wv   = tid >> 6;
    const int blk  = blockIdx.x;
    const int b    = blk >> 8;
    const int h    = blk & 255;
    const int nlo  = lane & 31;
    const int half = lane >> 5;

    const float* gx = g + (size_t)(b * OO) * 256;
    const float* gy = g + (size_t)BB * OO * 256 + (size_t)(b * OO) * 256;

    __shared__ float gxs[OO];
    if (tid < OO) gxs[tid] = gx[tid * 256 + h];

    short8v wf[2][4];
    #pragma unroll
    for (int ot = 0; ot < 2; ++ot) {
        const int o = ot * 32 + nlo;
        const float* wrow = mw + o * CC + 8 * half;
        #pragma unroll
        for (int kb = 0; kb < 4; ++kb) {
            short8v wi;
            #pragma unroll
            for (int i = 0; i < 8; ++i)
                wi[i] = f2bf_s(wrow[kb * 16 + i]);
            wf[ot][kb] = wi;
        }
    }
    __syncthreads();

    const float* xb = x + (size_t)b * CC * (HH * WW) + (size_t)h * WW;
    float*       ob = out + (size_t)b * OO * (HH * WW) + (size_t)h * WW;

    const int w0a = wv * 64;
    const int w0b = wv * 64 + 32;

    float xv[32];
    #pragma unroll
    for (int kb = 0; kb < 4; ++kb)
        #pragma unroll
        for (int i = 0; i < 8; ++i) {
            const int c = kb * 16 + 8 * half + i;
            xv[kb * 8 + i] = xb[(size_t)c * (HH * WW) + w0a + nlo];
        }

    short8v xh[4];
    #pragma unroll
    for (int kb = 0; kb < 4; ++kb) {
        short8v xi;
        #pragma unroll
        for (int i = 0; i < 8; ++i) xi[i] = f2bf_s(xv[kb * 8 + i]);
        xh[kb] = xi;
    }

    #pragma unroll
    for (int kb = 0; kb < 4; ++kb)
        #pragma unroll
        for (int i = 0; i < 8; ++i) {
            const int c = kb * 16 + 8 * half + i;
            xv[kb * 8 + i] = xb[(size_t)c * (HH * WW) + w0b + nlo];
        }

    f32x16 acc;

    #pragma unroll
    for (int i = 0; i < 16; ++i) acc[i] = 0.f;
    #pragma unroll
    for (int kb = 0; kb < 4; ++kb)
        acc = __builtin_amdgcn_mfma_f32_32x32x16_bf16(wf[0][kb], xh[kb], acc, 0, 0, 0);
    #pragma unroll
    for (int r = 0; r < 16; ++r) {
        const int o = (r & 3) + 8 * (r >> 2) + 4 * half;
        const float v = acc[r] + gxs[o] + gy[o * 256 + w0a + nlo];
        __builtin_nontemporal_store(v, &ob[(size_t)o * (HH * WW) + w0a + nlo]);
    }

    #pragma unroll
    for (int i = 0; i < 16; ++i) acc[i] = 0.f;
    #pragma unroll
    for (int kb = 0; kb < 4; ++kb)
        acc = __builtin_amdgcn_mfma_f32_32x32x16_bf16(wf[1][kb], xh[kb], acc, 0, 0, 0);
    #pragma unroll
    for (int r = 0; r < 16; ++r) {
        const int o = 32 + (r & 3) + 8 * (r >> 2) + 4 * half;
        const float v = acc[r] + gxs[o] + gy[o * 256 + w0a + nlo];
        __builtin_nontemporal_store(v, &ob[(size_t)o * (HH * WW) + w0a + nlo]);
    }

    #pragma unroll
    for (int kb = 0; kb < 4; ++kb) {
        short8v xi;
        #pragma unroll
        for (int i = 0; i < 8; ++i) xi[i] = f2bf_s(xv[kb * 8 + i]);
        xh[kb] = xi;
    }

    #pragma unroll
    for (int i = 0; i < 16; ++i) acc[i] = 0.f;
    #pragma unroll
    for (int kb = 0; kb < 4; ++kb)
        acc = __builtin_amdgcn_mfma_f32_32x32x16_bf16(wf[0][kb], xh[kb], acc, 0, 0, 0);
    #pragma unroll
    for (int r = 0; r < 16; ++r) {
        const int o = (r & 3) + 8 * (r >> 2) + 4 * half;
        const float v = acc[r] + gxs[o] + gy[o * 256 + w0b + nlo];
        __builtin_nontemporal_store(v, &ob[(size_t)o * (HH * WW) + w0b + nlo]);
    }

    #pragma unroll
    for (int i = 0; i < 16; ++i) acc[i] = 0.f;
    #pragma unroll
    for (int kb = 0; kb < 4; ++kb)
        acc = __builtin_amdgcn_mfma_f32_32x32x16_bf16(wf[1][kb], xh[kb], acc, 0, 0, 0);
    #pragma unroll
    for (int r = 0; r < 16; ++r) {
        const int o = 32 + (r & 3) + 8 * (r >> 2) + 4 * half;
        const float v = acc[r] + gxs[o] + gy[o * 256 + w0b + nlo];
        __builtin_nontemporal_store(v, &ob[(size_t)o * (HH * WW) + w0b + nlo]);
    }
}

// ---------------------------------------------------------------------------
extern "C" void kernel_launch(void* const* d_in, const int* in_sizes, int n_in,
                              void* d_out, int out_size, void* d_ws, size_t ws_size,
                              hipStream_t stream) {
    const float* x    = (const float*)d_in[0];
    const float* wxr  = (const float*)d_in[1];
    const float* wxi  = (const float*)d_in[2];
    const float* wyr  = (const float*)d_in[3];
    const float* wyi  = (const float*)d_in[4];
    const float* mixw = (const float*)d_in[5];
    const float* mixb = (const float*)d_in[6];
    float* out = (float*)d_out;
    float* ws  = (float*)d_ws;

    float* pft = ws + WS_PFT;
    float* g   = ws + WS_G;

    k_means_dft<<<BB * CC * 4, 256, 0, stream>>>(x, pft);
    k_mixsynth<<<2 * BB * OO, 256, 0, stream>>>(pft, wxr, wxi, wyr, wyi, mixb, g);
    k_final_mfma<<<BB * 256, 256, 0, stream>>>(x, mixw, g, out);
}

// Round 12
// 86.455 us; speedup vs baseline: 1.2844x; 1.0099x over previous
//
#include <hip/hip_runtime.h>
#include <hip/hip_bf16.h>
#include <cstddef>

// Problem constants
#define BB 8
#define CC 64
#define OO 64
#define HH 256
#define WW 256
#define MODES 16
#define NXCD 8

// Workspace layout (float offsets)
//  [0)       pft [B*C][4][2][16][2]  131072   (per-stripe partial spectra)
//  [131072)  g   [2][B][O][256]      262144
#define WS_PFT 0
#define WS_G   131072

#define TWO_PI 6.2831853071795864769f

typedef __attribute__((ext_vector_type(8)))  short short8v;
typedef __attribute__((ext_vector_type(16))) float f32x16;

// f32 -> bf16 bits via HIP builtin (RNE). NO inline asm (round-7 lesson).
__device__ __forceinline__ short f2bf_s(float v) {
    return (short)__builtin_bit_cast(unsigned short, __float2bfloat16(v));
}

// XCD-affinity swizzle (bijective; all our grids are multiples of 8).
// HW round-robins blockIdx%8 across XCDs -> XCD k gets work chunk
// [k*nwg/8, (k+1)*nwg/8). With B=8 and work id = b*rows+h, each XCD owns
// exactly one batch: contiguous x reads + L2-resident per-batch g tables.
__device__ __forceinline__ int xcd_swz(int bid, int nwg) {
    return (bid & (NXCD - 1)) * (nwg / NXCD) + (bid >> 3);
}

// ---------------------------------------------------------------------------
// K1: grid = B*C*4. Work block j of slice bc handles rows [j*64, j*64+64).
// One pass produces BOTH 16-mode partial spectra (DFT linear in stripes):
//   prow[k] = sum_{r<64} rowmean(h0+r) e^{-i2pi k(h0+r)/256}   (br=0)
//   pcol[k] = sum_{w}    colpartial(w) e^{-i2pi k w/256}       (br=1)
__global__ void k_means_dft(const float* __restrict__ x,
                            float* __restrict__ pft) { // [512][4][2][16][2]
    const int blk = xcd_swz(blockIdx.x, BB * CC * 4);  // bc*4 + j
    const int bc  = blk >> 2;
    const int j   = blk & 3;
    const int t   = threadIdx.x;
    const int wave = t >> 6;
    const int lane = t & 63;
    const float* xs = x + (size_t)bc * (HH * WW);

    __shared__ float colsum[4][WW];
    __shared__ float cs[WW];
    __shared__ float rm[64];

    float c0 = 0.f, c1 = 0.f, c2 = 0.f, c3 = 0.f;
    const int h0 = j * 64 + wave * 16;
    for (int r = 0; r < 16; ++r) {
        const int h = h0 + r;
        const float4 v = *reinterpret_cast<const float4*>(xs + (size_t)h * WW + lane * 4);
        c0 += v.x; c1 += v.y; c2 += v.z; c3 += v.w;
        float rs = (v.x + v.y) + (v.z + v.w);
        #pragma unroll
        for (int off = 32; off > 0; off >>= 1) rs += __shfl_xor(rs, off, 64);
        if (lane == 0) rm[wave * 16 + r] = rs * (1.0f / WW);   // row mean
    }
    colsum[wave][lane * 4 + 0] = c0;
    colsum[wave][lane * 4 + 1] = c1;
    colsum[wave][lane * 4 + 2] = c2;
    colsum[wave][lane * 4 + 3] = c3;
    __syncthreads();
    cs[t] = (colsum[0][t] + colsum[1][t]) + (colsum[2][t] + colsum[3][t]);
    __syncthreads();

    // 16-mode partial DFTs. thread t: mode k = t>>4, sub-chunk = t&15.
    const int k   = t >> 4;
    const int sub = t & 15;
    const float wk = TWO_PI * (float)k / 256.0f;

    // column-branch: 256-point DFT of this stripe's column partial sums
    float cre = 0.f, cim = 0.f;
    #pragma unroll
    for (int i = 0; i < 16; ++i) {
        const int w = sub * 16 + i;
        float s, c;
        sincosf(wk * (float)w, &s, &c);
        cre += cs[w] * c;
        cim -= cs[w] * s;
    }
    // row-branch: 64-point partial DFT of this stripe's row means (global h!)
    float rre = 0.f, rim = 0.f;
    #pragma unroll
    for (int i = 0; i < 4; ++i) {
        const int r = sub * 4 + i;
        float s, c;
        sincosf(wk * (float)(j * 64 + r), &s, &c);
        rre += rm[r] * c;
        rim -= rm[r] * s;
    }
    #pragma unroll
    for (int m = 1; m < 16; m <<= 1) {
        cre += __shfl_xor(cre, m, 64);
        cim += __shfl_xor(cim, m, 64);
        rre += __shfl_xor(rre, m, 64);
        rim += __shfl_xor(rim, m, 64);
    }
    if (sub == 0) {
        float* p = pft + (((size_t)blk * 2 + 0) * 16 + k) * 2;
        p[0] = rre; p[1] = rim;
        p += 32;                         // br=1 slot
        p[0] = cre; p[1] = cim;
    }
}

// ---------------------------------------------------------------------------
// K2: fused modemix+synth, grid = 2*B*O = 1024 blocks (one per (br,b,o)).
__global__ void k_mixsynth(const float* __restrict__ pft,
                           const float* __restrict__ wxr, const float* __restrict__ wxi,
                           const float* __restrict__ wyr, const float* __restrict__ wyi,
                           const float* __restrict__ mb,
                           float* __restrict__ g) {
    const int blk = xcd_swz(blockIdx.x, 2 * BB * OO);  // (br*8 + b)*64 + o
    const int bb  = blk >> 6;
    const int br  = bb >> 3;
    const int b   = bb & 7;
    const int o   = blk & 63;
    const int t   = threadIdx.x;
    const int k   = t & 15;
    const int cg  = t >> 4;              // 0..15, 4 channels each
    const int wave = t >> 6;
    const int lane = t & 63;

    const float* wr = br ? wyr : wxr;
    const float* wi = br ? wyi : wxi;
    // row branch: rm already /W, ortho 1/sqrt(256) -> 1/16
    // col branch: raw sums over h -> 1/256, ortho -> 1/16
    const float norm = br ? (1.0f / (16.0f * 256.0f)) : (1.0f / 16.0f);

    // partial box over this thread's 4 channels
    float are = 0.f, aim = 0.f;
    #pragma unroll
    for (int cc = 0; cc < 4; ++cc) {
        const int c = cg * 4 + cc;
        float re = 0.f, im = 0.f;
        #pragma unroll
        for (int j = 0; j < 4; ++j) {
            const float* p = pft +
                ((((size_t)(b * 64 + c) * 4 + j) * 2 + br) * 16 + k) * 2;
            re += p[0]; im += p[1];
        }
        re *= norm; im *= norm;
        const float wrv = wr[(c * OO + o) * MODES + k];
        const float wiv = wi[(c * OO + o) * MODES + k];
        are += re * wrv - im * wiv;
        aim += re * wiv + im * wrv;
    }
    // reduce over cg: within wave (cg +4, +8 eq: lanes 16/32 apart), then waves
    are += __shfl_xor(are, 16, 64); aim += __shfl_xor(aim, 16, 64);
    are += __shfl_xor(are, 32, 64); aim += __shfl_xor(aim, 32, 64);

    __shared__ float wre[4][16], wim[4][16];
    __shared__ float bre[16], bim[16];
    if (lane < 16) { wre[wave][lane] = are; wim[wave][lane] = aim; }
    __syncthreads();
    if (t < 16) {
        bre[t] = (wre[0][t] + wre[1][t]) + (wre[2][t] + wre[3][t]);
        bim[t] = (wim[0][t] + wim[1][t]) + (wim[2][t] + wim[3][t]);
    }
    __syncthreads();

    // synth: thread t = position
    float acc = bre[0];
    const float wt = TWO_PI * (float)t / 256.0f;
    #pragma unroll
    for (int kk = 1; kk < MODES; ++kk) {
        float s, c;
        sincosf(wt * (float)kk, &s, &c);
        acc += 2.0f * (bre[kk] * c - bim[kk] * s);
    }
    float v = acc * (1.0f / 16.0f);
    if (br == 0) v += mb[o];
    g[(size_t)blk * 256 + t] = v;
}

// ---------------------------------------------------------------------------
// K3: MFMA epilogue GEMM — round 8's register version + XCD-batch affinity.
// out[b,o,h,w] = sum_c mw[o,c] x[b,c,h,w] + gx'[b,o,h] + gy[b,o,w]
__global__ void __launch_bounds__(256) k_final_mfma(
        const float* __restrict__ x,
        const float* __restrict__ mw,   // [O][C]
        const float* __restrict__ g,    // [2][B][O][256]
        float* __restrict__ out) {
    const int tid  = threadIdx.x;
    const int lane = tid & 63;
    const int wv   = tid >> 6;
    const int blk  = xcd_swz(blockIdx.x, BB * 256);  // b*256 + h; XCD == batch
    const int b    = blk >> 8;
    const int h    = blk & 255;
    const int nlo  = lane & 31;
    const int half = lane >> 5;

    const float* gx = g + (size_t)(b * OO) * 256;
    const float* gy = g + (size_t)BB * OO * 256 + (size_t)(b * OO) * 256;

    __shared__ float gxs[OO];
    if (tid < OO) gxs[tid] = gx[tid * 256 + h];

    short8v wf[2][4];
    #pragma unroll
    for (int ot = 0; ot < 2; ++ot) {
        const int o = ot * 32 + nlo;
        const float* wrow = mw + o * CC + 8 * half;
        #pragma unroll
        for (int kb = 0; kb < 4; ++kb) {
            short8v wi;
            #pragma unroll
            for (int i = 0; i < 8; ++i)
                wi[i] = f2bf_s(wrow[kb * 16 + i]);
            wf[ot][kb] = wi;
        }
    }
    __syncthreads();

    const float* xb = x + (size_t)b * CC * (HH * WW) + (size_t)h * WW;
    float*       ob = out + (size_t)b * OO * (HH * WW) + (size_t)h * WW;

    const int w0a = wv * 64;
    const int w0b = wv * 64 + 32;

    float xv[32];
    #pragma unroll
    for (int kb = 0; kb < 4; ++kb)
        #pragma unroll
        for (int i = 0; i < 8; ++i) {
            const int c = kb * 16 + 8 * half + i;
            xv[kb * 8 + i] = xb[(size_t)c * (HH * WW) + w0a + nlo];
        }

    short8v xh[4];
    #pragma unroll
    for (int kb = 0; kb < 4; ++kb) {
        short8v xi;
        #pragma unroll
        for (int i = 0; i < 8; ++i) xi[i] = f2bf_s(xv[kb * 8 + i]);
        xh[kb] = xi;
    }

    #pragma unroll
    for (int kb = 0; kb < 4; ++kb)
        #pragma unroll
        for (int i = 0; i < 8; ++i) {
            const int c = kb * 16 + 8 * half + i;
            xv[kb * 8 + i] = xb[(size_t)c * (HH * WW) + w0b + nlo];
        }

    f32x16 acc;

    #pragma unroll
    for (int i = 0; i < 16; ++i) acc[i] = 0.f;
    #pragma unroll
    for (int kb = 0; kb < 4; ++kb)
        acc = __builtin_amdgcn_mfma_f32_32x32x16_bf16(wf[0][kb], xh[kb], acc, 0, 0, 0);
    #pragma unroll
    for (int r = 0; r < 16; ++r) {
        const int o = (r & 3) + 8 * (r >> 2) + 4 * half;
        const float v = acc[r] + gxs[o] + gy[o * 256 + w0a + nlo];
        __builtin_nontemporal_store(v, &ob[(size_t)o * (HH * WW) + w0a + nlo]);
    }

    #pragma unroll
    for (int i = 0; i < 16; ++i) acc[i] = 0.f;
    #pragma unroll
    for (int kb = 0; kb < 4; ++kb)
        acc = __builtin_amdgcn_mfma_f32_32x32x16_bf16(wf[1][kb], xh[kb], acc, 0, 0, 0);
    #pragma unroll
    for (int r = 0; r < 16; ++r) {
        const int o = 32 + (r & 3) + 8 * (r >> 2) + 4 * half;
        const float v = acc[r] + gxs[o] + gy[o * 256 + w0a + nlo];
        __builtin_nontemporal_store(v, &ob[(size_t)o * (HH * WW) + w0a + nlo]);
    }

    #pragma unroll
    for (int kb = 0; kb < 4; ++kb) {
        short8v xi;
        #pragma unroll
        for (int i = 0; i < 8; ++i) xi[i] = f2bf_s(xv[kb * 8 + i]);
        xh[kb] = xi;
    }

    #pragma unroll
    for (int i = 0; i < 16; ++i) acc[i] = 0.f;
    #pragma unroll
    for (int kb = 0; kb < 4; ++kb)
        acc = __builtin_amdgcn_mfma_f32_32x32x16_bf16(wf[0][kb], xh[kb], acc, 0, 0, 0);
    #pragma unroll
    for (int r = 0; r < 16; ++r) {
        const int o = (r & 3) + 8 * (r >> 2) + 4 * half;
        const float v = acc[r] + gxs[o] + gy[o * 256 + w0b + nlo];
        __builtin_nontemporal_store(v, &ob[(size_t)o * (HH * WW) + w0b + nlo]);
    }

    #pragma unroll
    for (int i = 0; i < 16; ++i) acc[i] = 0.f;
    #pragma unroll
    for (int kb = 0; kb < 4; ++kb)
        acc = __builtin_amdgcn_mfma_f32_32x32x16_bf16(wf[1][kb], xh[kb], acc, 0, 0, 0);
    #pragma unroll
    for (int r = 0; r < 16; ++r) {
        const int o = 32 + (r & 3) + 8 * (r >> 2) + 4 * half;
        const float v = acc[r] + gxs[o] + gy[o * 256 + w0b + nlo];
        __builtin_nontemporal_store(v, &ob[(size_t)o * (HH * WW) + w0b + nlo]);
    }
}

// ---------------------------------------------------------------------------
extern "C" void kernel_launch(void* const* d_in, const int* in_sizes, int n_in,
                              void* d_out, int out_size, void* d_ws, size_t ws_size,
                              hipStream_t stream) {
    const float* x    = (const float*)d_in[0];
    const float* wxr  = (const float*)d_in[1];
    const float* wxi  = (const float*)d_in[2];
    const float* wyr  = (const float*)d_in[3];
    const float* wyi  = (const float*)d_in[4];
    const float* mixw = (const float*)d_in[5];
    const float* mixb = (const float*)d_in[6];
    float* out = (float*)d_out;
    float* ws  = (float*)d_ws;

    float* pft = ws + WS_PFT;
    float* g   = ws + WS_G;

    k_means_dft<<<BB * CC * 4, 256, 0, stream>>>(x, pft);
    k_mixsynth<<<2 * BB * OO, 256, 0, stream>>>(pft, wxr, wxi, wyr, wyi, mixb, g);
    k_final_mfma<<<BB * 256, 256, 0, stream>>>(x, mixw, g, out);
}

// Round 13
// 80.473 us; speedup vs baseline: 1.3799x; 1.0743x over previous
//
#include <hip/hip_runtime.h>
#include <hip/hip_bf16.h>
#include <cstddef>

// Problem constants
#define BB 8
#define CC 64
#define OO 64
#define HH 256
#define WW 256
#define MODES 16
#define NXCD 8

// Workspace layout (float offsets)
//  [0)       pft [B*C][4][2][16][2]  131072   (per-stripe partial spectra)
//  [131072)  g   [2][B][O][256]      262144
#define WS_PFT 0
#define WS_G   131072

#define TWO_PI 6.2831853071795864769f

typedef __attribute__((ext_vector_type(8)))  short short8v;
typedef __attribute__((ext_vector_type(16))) float f32x16;

// f32 -> bf16 bits via HIP builtin (RNE). NO inline asm (round-7 lesson).
__device__ __forceinline__ short f2bf_s(float v) {
    return (short)__builtin_bit_cast(unsigned short, __float2bfloat16(v));
}

// XCD-affinity swizzle — used ONLY in k_final (its blocks share per-batch
// gx/gy tables -> L2 reuse). k_means/k_mixsynth blocks share nothing; the
// r12 swizzle there scattered the read stream for no reuse gain (reverted).
__device__ __forceinline__ int xcd_swz(int bid, int nwg) {
    return (bid & (NXCD - 1)) * (nwg / NXCD) + (bid >> 3);
}

// ---------------------------------------------------------------------------
// K1: grid = B*C*4. Block j of slice bc handles rows [j*64, j*64+64).
// One pass produces BOTH 16-mode partial spectra (DFT linear in stripes):
//   prow[k] = sum_{r<64} rowmean(h0+r) e^{-i2pi k(h0+r)/256}   (br=0)
//   pcol[k] = sum_{w}    colpartial(w) e^{-i2pi k w/256}       (br=1)
// r13 restructure: row sums go through LDS partials reduced ONCE in
// parallel (was: serial 6-step shfl chain per row blocking the load
// pipeline); DFT-tail LDS reads strided (conflict-free, was 8-way).
__global__ void k_means_dft(const float* __restrict__ x,
                            float* __restrict__ pft) { // [512][4][2][16][2]
    const int blk = blockIdx.x;                  // bc*4 + j
    const int bc  = blk >> 2;
    const int j   = blk & 3;
    const int t   = threadIdx.x;
    const int wave = t >> 6;
    const int lane = t & 63;
    const float* xs = x + (size_t)bc * (HH * WW);

    __shared__ float rowp[64][65];   // [row-in-block][lane] 4-col partials (+pad)
    __shared__ float colsum[4][WW];
    __shared__ float cs[WW];
    __shared__ float rm[64];

    float c0 = 0.f, c1 = 0.f, c2 = 0.f, c3 = 0.f;
    const int rbase = wave * 16;                 // row-in-block base
    const int h0 = j * 64 + rbase;
    #pragma unroll
    for (int r = 0; r < 16; ++r) {
        const float4 v = *reinterpret_cast<const float4*>(
            xs + (size_t)(h0 + r) * WW + lane * 4);
        c0 += v.x; c1 += v.y; c2 += v.z; c3 += v.w;
        rowp[rbase + r][lane] = (v.x + v.y) + (v.z + v.w);  // no cross-lane op
    }
    colsum[wave][lane * 4 + 0] = c0;
    colsum[wave][lane * 4 + 1] = c1;
    colsum[wave][lane * 4 + 2] = c2;
    colsum[wave][lane * 4 + 3] = c3;
    __syncthreads();

    // Parallel row reduction: thread t -> row = t>>2, quarter q = t&3.
    {
        const int row = t >> 2;
        const int q   = t & 3;
        float s = 0.f;
        #pragma unroll
        for (int i = 0; i < 16; ++i) s += rowp[row][q * 16 + i];
        s += __shfl_xor(s, 1, 64);
        s += __shfl_xor(s, 2, 64);
        if (q == 0) rm[row] = s * (1.0f / WW);   // row mean
    }
    cs[t] = (colsum[0][t] + colsum[1][t]) + (colsum[2][t] + colsum[3][t]);
    __syncthreads();

    // 16-mode partial DFTs. thread t: mode k = t>>4, sub-chunk = t&15.
    // Strided sample assignment (w = i*16+sub): 16 consecutive LDS addrs
    // per iteration across the 16 subs -> conflict-free.
    const int k   = t >> 4;
    const int sub = t & 15;
    const float wk = TWO_PI * (float)k / 256.0f;

    float cre = 0.f, cim = 0.f;
    #pragma unroll
    for (int i = 0; i < 16; ++i) {
        const int w = i * 16 + sub;
        float s, c;
        sincosf(wk * (float)w, &s, &c);
        cre += cs[w] * c;
        cim -= cs[w] * s;
    }
    float rre = 0.f, rim = 0.f;
    #pragma unroll
    for (int i = 0; i < 4; ++i) {
        const int r = i * 16 + sub;
        float s, c;
        sincosf(wk * (float)(j * 64 + r), &s, &c);
        rre += rm[r] * c;
        rim -= rm[r] * s;
    }
    #pragma unroll
    for (int m = 1; m < 16; m <<= 1) {
        cre += __shfl_xor(cre, m, 64);
        cim += __shfl_xor(cim, m, 64);
        rre += __shfl_xor(rre, m, 64);
        rim += __shfl_xor(rim, m, 64);
    }
    if (sub == 0) {
        float* p = pft + (((size_t)blk * 2 + 0) * 16 + k) * 2;
        p[0] = rre; p[1] = rim;
        p += 32;                         // br=1 slot
        p[0] = cre; p[1] = cim;
    }
}

// ---------------------------------------------------------------------------
// K2: fused modemix+synth, grid = 2*B*O = 1024 blocks (one per (br,b,o)).
__global__ void k_mixsynth(const float* __restrict__ pft,
                           const float* __restrict__ wxr, const float* __restrict__ wxi,
                           const float* __restrict__ wyr, const float* __restrict__ wyi,
                           const float* __restrict__ mb,
                           float* __restrict__ g) {
    const int blk = blockIdx.x;          // (br*8 + b)*64 + o
    const int bb  = blk >> 6;
    const int br  = bb >> 3;
    const int b   = bb & 7;
    const int o   = blk & 63;
    const int t   = threadIdx.x;
    const int k   = t & 15;
    const int cg  = t >> 4;              // 0..15, 4 channels each
    const int wave = t >> 6;
    const int lane = t & 63;

    const float* wr = br ? wyr : wxr;
    const float* wi = br ? wyi : wxi;
    // row branch: rm already /W, ortho 1/sqrt(256) -> 1/16
    // col branch: raw sums over h -> 1/256, ortho -> 1/16
    const float norm = br ? (1.0f / (16.0f * 256.0f)) : (1.0f / 16.0f);

    float are = 0.f, aim = 0.f;
    #pragma unroll
    for (int cc = 0; cc < 4; ++cc) {
        const int c = cg * 4 + cc;
        float re = 0.f, im = 0.f;
        #pragma unroll
        for (int j = 0; j < 4; ++j) {
            const float* p = pft +
                ((((size_t)(b * 64 + c) * 4 + j) * 2 + br) * 16 + k) * 2;
            re += p[0]; im += p[1];
        }
        re *= norm; im *= norm;
        const float wrv = wr[(c * OO + o) * MODES + k];
        const float wiv = wi[(c * OO + o) * MODES + k];
        are += re * wrv - im * wiv;
        aim += re * wiv + im * wrv;
    }
    are += __shfl_xor(are, 16, 64); aim += __shfl_xor(aim, 16, 64);
    are += __shfl_xor(are, 32, 64); aim += __shfl_xor(aim, 32, 64);

    __shared__ float wre[4][16], wim[4][16];
    __shared__ float bre[16], bim[16];
    if (lane < 16) { wre[wave][lane] = are; wim[wave][lane] = aim; }
    __syncthreads();
    if (t < 16) {
        bre[t] = (wre[0][t] + wre[1][t]) + (wre[2][t] + wre[3][t]);
        bim[t] = (wim[0][t] + wim[1][t]) + (wim[2][t] + wim[3][t]);
    }
    __syncthreads();

    float acc = bre[0];
    const float wt = TWO_PI * (float)t / 256.0f;
    #pragma unroll
    for (int kk = 1; kk < MODES; ++kk) {
        float s, c;
        sincosf(wt * (float)kk, &s, &c);
        acc += 2.0f * (bre[kk] * c - bim[kk] * s);
    }
    float v = acc * (1.0f / 16.0f);
    if (br == 0) v += mb[o];
    g[(size_t)blk * 256 + t] = v;
}

// ---------------------------------------------------------------------------
// K3: MFMA epilogue GEMM — round 8's register version + XCD-batch affinity
// (kept: per-batch gx/gy tables become L2-resident per XCD).
// out[b,o,h,w] = sum_c mw[o,c] x[b,c,h,w] + gx'[b,o,h] + gy[b,o,w]
__global__ void __launch_bounds__(256) k_final_mfma(
        const float* __restrict__ x,
        const float* __restrict__ mw,   // [O][C]
        const float* __restrict__ g,    // [2][B][O][256]
        float* __restrict__ out) {
    const int tid  = threadIdx.x;
    const int lane = tid & 63;
    const int wv   = tid >> 6;
    const int blk  = xcd_swz(blockIdx.x, BB * 256);  // b*256 + h; XCD == batch
    const int b    = blk >> 8;
    const int h    = blk & 255;
    const int nlo  = lane & 31;
    const int half = lane >> 5;

    const float* gx = g + (size_t)(b * OO) * 256;
    const float* gy = g + (size_t)BB * OO * 256 + (size_t)(b * OO) * 256;

    __shared__ float gxs[OO];
    if (tid < OO) gxs[tid] = gx[tid * 256 + h];

    short8v wf[2][4];
    #pragma unroll
    for (int ot = 0; ot < 2; ++ot) {
        const int o = ot * 32 + nlo;
        const float* wrow = mw + o * CC + 8 * half;
        #pragma unroll
        for (int kb = 0; kb < 4; ++kb) {
            short8v wi;
            #pragma unroll
            for (int i = 0; i < 8; ++i)
                wi[i] = f2bf_s(wrow[kb * 16 + i]);
            wf[ot][kb] = wi;
        }
    }
    __syncthreads();

    const float* xb = x + (size_t)b * CC * (HH * WW) + (size_t)h * WW;
    float*       ob = out + (size_t)b * OO * (HH * WW) + (size_t)h * WW;

    const int w0a = wv * 64;
    const int w0b = wv * 64 + 32;

    float xv[32];
    #pragma unroll
    for (int kb = 0; kb < 4; ++kb)
        #pragma unroll
        for (int i = 0; i < 8; ++i) {
            const int c = kb * 16 + 8 * half + i;
            xv[kb * 8 + i] = xb[(size_t)c * (HH * WW) + w0a + nlo];
        }

    short8v xh[4];
    #pragma unroll
    for (int kb = 0; kb < 4; ++kb) {
        short8v xi;
        #pragma unroll
        for (int i = 0; i < 8; ++i) xi[i] = f2bf_s(xv[kb * 8 + i]);
        xh[kb] = xi;
    }

    #pragma unroll
    for (int kb = 0; kb < 4; ++kb)
        #pragma unroll
        for (int i = 0; i < 8; ++i) {
            const int c = kb * 16 + 8 * half + i;
            xv[kb * 8 + i] = xb[(size_t)c * (HH * WW) + w0b + nlo];
        }

    f32x16 acc;

    #pragma unroll
    for (int i = 0; i < 16; ++i) acc[i] = 0.f;
    #pragma unroll
    for (int kb = 0; kb < 4; ++kb)
        acc = __builtin_amdgcn_mfma_f32_32x32x16_bf16(wf[0][kb], xh[kb], acc, 0, 0, 0);
    #pragma unroll
    for (int r = 0; r < 16; ++r) {
        const int o = (r & 3) + 8 * (r >> 2) + 4 * half;
        const float v = acc[r] + gxs[o] + gy[o * 256 + w0a + nlo];
        __builtin_nontemporal_store(v, &ob[(size_t)o * (HH * WW) + w0a + nlo]);
    }

    #pragma unroll
    for (int i = 0; i < 16; ++i) acc[i] = 0.f;
    #pragma unroll
    for (int kb = 0; kb < 4; ++kb)
        acc = __builtin_amdgcn_mfma_f32_32x32x16_bf16(wf[1][kb], xh[kb], acc, 0, 0, 0);
    #pragma unroll
    for (int r = 0; r < 16; ++r) {
        const int o = 32 + (r & 3) + 8 * (r >> 2) + 4 * half;
        const float v = acc[r] + gxs[o] + gy[o * 256 + w0a + nlo];
        __builtin_nontemporal_store(v, &ob[(size_t)o * (HH * WW) + w0a + nlo]);
    }

    #pragma unroll
    for (int kb = 0; kb < 4; ++kb) {
        short8v xi;
        #pragma unroll
        for (int i = 0; i < 8; ++i) xi[i] = f2bf_s(xv[kb * 8 + i]);
        xh[kb] = xi;
    }

    #pragma unroll
    for (int i = 0; i < 16; ++i) acc[i] = 0.f;
    #pragma unroll
    for (int kb = 0; kb < 4; ++kb)
        acc = __builtin_amdgcn_mfma_f32_32x32x16_bf16(wf[0][kb], xh[kb], acc, 0, 0, 0);
    #pragma unroll
    for (int r = 0; r < 16; ++r) {
        const int o = (r & 3) + 8 * (r >> 2) + 4 * half;
        const float v = acc[r] + gxs[o] + gy[o * 256 + w0b + nlo];
        __builtin_nontemporal_store(v, &ob[(size_t)o * (HH * WW) + w0b + nlo]);
    }

    #pragma unroll
    for (int i = 0; i < 16; ++i) acc[i] = 0.f;
    #pragma unroll
    for (int kb = 0; kb < 4; ++kb)
        acc = __builtin_amdgcn_mfma_f32_32x32x16_bf16(wf[1][kb], xh[kb], acc, 0, 0, 0);
    #pragma unroll
    for (int r = 0; r < 16; ++r) {
        const int o = 32 + (r & 3) + 8 * (r >> 2) + 4 * half;
        const float v = acc[r] + gxs[o] + gy[o * 256 + w0b + nlo];
        __builtin_nontemporal_store(v, &ob[(size_t)o * (HH * WW) + w0b + nlo]);
    }
}

// ---------------------------------------------------------------------------
extern "C" void kernel_launch(void* const* d_in, const int* in_sizes, int n_in,
                              void* d_out, int out_size, void* d_ws, size_t ws_size,
                              hipStream_t stream) {
    const float* x    = (const float*)d_in[0];
    const float* wxr  = (const float*)d_in[1];
    const float* wxi  = (const float*)d_in[2];
    const float* wyr  = (const float*)d_in[3];
    const float* wyi  = (const float*)d_in[4];
    const float* mixw = (const float*)d_in[5];
    const float* mixb = (const float*)d_in[6];
    float* out = (float*)d_out;
    float* ws  = (float*)d_ws;

    float* pft = ws + WS_PFT;
    float* g   = ws + WS_G;

    k_means_dft<<<BB * CC * 4, 256, 0, stream>>>(x, pft);
    k_mixsynth<<<2 * BB * OO, 256, 0, stream>>>(pft, wxr, wxi, wyr, wyi, mixb, g);
    k_final_mfma<<<BB * 256, 256, 0, stream>>>(x, mixw, g, out);
}